// Round 5
// baseline (292.108 us; speedup 1.0000x reference)
//
#include <hip/hip_runtime.h>
#include <math.h>

#define NNODES 50000
#define NEDGES 400000
#define NGRAPHS 512
#define FDIM 32

// C(31, k) exact
__device__ __constant__ float BINOM31[32] = {
    1.f, 31.f, 465.f, 4495.f, 31465.f, 169911.f, 736281.f, 2629575.f,
    7888725.f, 20160075.f, 44352165.f, 84672315.f, 141120525.f, 206253075.f,
    265182525.f, 300540195.f, 300540195.f, 265182525.f, 206253075.f,
    141120525.f, 84672315.f, 44352165.f, 20160075.f, 7888725.f, 2629575.f,
    736281.f, 169911.f, 31465.f, 4495.f, 465.f, 31.f, 1.f
};

__device__ __forceinline__ float fast_rcp(float x) {
    return __builtin_amdgcn_rcpf(x);
}
__device__ __forceinline__ float silu(float x) {
    return x * fast_rcp(1.0f + __expf(-x));
}

// One wave per 64-edge chunk. Scalar phase: one edge per lane (coalesced idx,
// 64 pos-gathers in flight), park (scale, r, row, dst) in wave-private LDS.
// Broadcast phase: batches of 8 edges per half-wave — read 8 quads
// (ds_read_b128 broadcast), issue all 8 xin gathers, then 8 independent
// register-Horner chains overlap the load latency. Coeff matrix in 32 VGPRs.
__global__ __launch_bounds__(256) void edge_pass(
    const float* __restrict__ pos,
    const int* __restrict__ src_idx,
    const int* __restrict__ dst_idx,
    const float* __restrict__ Wp1,
    const float* __restrict__ Wp2,      // may be null (pass B)
    const float* __restrict__ xin,
    const int* __restrict__ zmap,       // may be null
    float* __restrict__ acc)
{
    __shared__ float4 quad[4][64];
    int tid  = threadIdx.x;
    int lane = tid & 63;
    int widx = tid >> 6;
    int f    = lane & 31;
    int half = lane >> 5;

    float C[32];
    #pragma unroll
    for (int k = 0; k < 32; ++k) {
        float w = Wp1[k * FDIM + f];
        if (Wp2) w += Wp2[k * FDIM + f];
        C[k] = BINOM31[k] * w;
    }

    int base = (blockIdx.x * 4 + widx) << 6;
    if (base >= NEDGES) return;

    int e = base + lane;                // NEDGES % 64 == 0: in-bounds
    int s = src_idx[e];
    int d = dst_idx[e];
    float dx = pos[3 * s]     - pos[3 * d];
    float dy = pos[3 * s + 1] - pos[3 * d + 1];
    float dz = pos[3 * s + 2] - pos[3 * d + 2];
    float r = sqrtf(dx * dx + dy * dy + dz * dz + 1e-12f);

    float scale = 0.0f;
    if (r < 5.0f) {
        float t = r * 0.2f;
        float q = fmaxf(1.0f - t * t, 1e-7f);
        float cut = __expf(1.0f - fast_rcp(q));
        float v = fast_rcp(r + 1.0f);
        float v2 = v * v, v4 = v2 * v2, v8 = v4 * v4, v16 = v8 * v8;
        scale = v16 * v8 * v4 * v2 * v * cut;
    }
    int row = zmap ? zmap[s] : s;

    quad[widx][lane] = make_float4(scale, r, __int_as_float(row),
                                   __int_as_float(d));
    // wave-private LDS region: compiler inserts the lgkmcnt wait; no barrier.

    #pragma unroll
    for (int b = 0; b < 32; b += 8) {
        float4 q[8];
        float xs[8];
        #pragma unroll
        for (int i = 0; i < 8; ++i)
            q[i] = quad[widx][2 * (b + i) + half];
        #pragma unroll
        for (int i = 0; i < 8; ++i)
            xs[i] = xin[__float_as_int(q[i].z) * FDIM + f];
        #pragma unroll
        for (int i = 0; i < 8; ++i) {
            float sj = q[i].x;
            if (sj != 0.0f) {
                float rj = q[i].y;
                float w = C[31];
                #pragma unroll
                for (int k = 30; k >= 0; --k)
                    w = fmaf(w, rj, C[k]);
                atomicAdd(&acc[__float_as_int(q[i].w) * FDIM + f],
                          sj * w * xs[i]);
            }
        }
    }
}

// Phase-A node update: thread-per-node, W via wave-uniform scalar loads.
// Liveness kept ~64 floats (y then t; x0 reloaded at the end) + (256,2)
// launch bounds so the compiler doesn't cap VGPRs at 64 and spill.
__global__ __launch_bounds__(256, 2) void node_a(
    const float* __restrict__ embed, const int* __restrict__ Z,
    const float* __restrict__ W1, const float* __restrict__ b1,
    const float* __restrict__ W2, const float* __restrict__ b2,
    const float* __restrict__ c0,
    const float* __restrict__ acc, float* __restrict__ x1buf)
{
    int n = blockIdx.x * blockDim.x + threadIdx.x;
    if (n >= NNODES) return;

    const float4* e4 = (const float4*)(embed + (size_t)Z[n] * FDIM);
    const float4* a4 = (const float4*)(acc + (size_t)n * FDIM);

    float y[32];
    #pragma unroll
    for (int i = 0; i < 8; ++i) {
        float4 xv = e4[i];
        float4 av = a4[i];
        y[4*i+0] = xv.x + av.x; y[4*i+1] = xv.y + av.y;
        y[4*i+2] = xv.z + av.z; y[4*i+3] = xv.w + av.w;
    }

    float t[32];
    #pragma unroll
    for (int ff = 0; ff < 32; ++ff) t[ff] = b1[ff];
    #pragma unroll
    for (int k = 0; k < 32; ++k) {
        #pragma unroll
        for (int ff = 0; ff < 32; ++ff)
            t[ff] = fmaf(y[k], W1[k * FDIM + ff], t[ff]);
    }
    #pragma unroll
    for (int ff = 0; ff < 32; ++ff) t[ff] = silu(t[ff]);  // gate@ch0 = silu

    // y dead — reuse as y2
    #pragma unroll
    for (int ff = 0; ff < 32; ++ff) y[ff] = b2[ff];
    #pragma unroll
    for (int k = 0; k < 32; ++k) {
        #pragma unroll
        for (int ff = 0; ff < 32; ++ff)
            y[ff] = fmaf(t[k], W2[k * FDIM + ff], y[ff]);
    }

    float sc = silu(c0[0]);
    float4* o4 = (float4*)(x1buf + (size_t)n * FDIM);
    #pragma unroll
    for (int i = 0; i < 8; ++i) {
        float4 xv = e4[i];               // reload x0 (L1-resident, 15 KB table)
        o4[i] = make_float4(fmaf(sc, y[4*i+0], xv.x),
                            fmaf(sc, y[4*i+1], xv.y),
                            fmaf(sc, y[4*i+2], xv.z),
                            fmaf(sc, y[4*i+3], xv.w));
    }
}

// Phase-B node update + readout + per-graph reduction. Thread-per-node,
// same liveness discipline as node_a.
__global__ __launch_bounds__(256, 2) void node_b(
    const float* __restrict__ W1, const float* __restrict__ b1,
    const float* __restrict__ W2, const float* __restrict__ b2,
    const float* __restrict__ c1,
    const float* __restrict__ Wro1, const float* __restrict__ bro1,
    const float* __restrict__ Wro2, const float* __restrict__ bro2,
    const float* __restrict__ abias, const int* __restrict__ Z,
    const int* __restrict__ segs,
    const float* __restrict__ acc, const float* __restrict__ x1buf,
    float* __restrict__ out)
{
    int n = blockIdx.x * blockDim.x + threadIdx.x;
    if (n >= NNODES) return;

    const float4* x4 = (const float4*)(x1buf + (size_t)n * FDIM);
    const float4* a4 = (const float4*)(acc + (size_t)n * FDIM);

    float y0[32];
    #pragma unroll
    for (int i = 0; i < 8; ++i) {
        float4 xv = x4[i];
        float4 av = a4[i];
        y0[4*i+0] = xv.x + av.x; y0[4*i+1] = xv.y + av.y;
        y0[4*i+2] = xv.z + av.z; y0[4*i+3] = xv.w + av.w;
    }

    float t[32];
    #pragma unroll
    for (int ff = 0; ff < 32; ++ff) t[ff] = b1[ff];
    #pragma unroll
    for (int k = 0; k < 32; ++k) {
        #pragma unroll
        for (int ff = 0; ff < 32; ++ff)
            t[ff] = fmaf(y0[k], W1[k * FDIM + ff], t[ff]);
    }
    #pragma unroll
    for (int ff = 0; ff < 32; ++ff) t[ff] = silu(t[ff]);

    // y0 dead — reuse as y0b
    #pragma unroll
    for (int ff = 0; ff < 32; ++ff) y0[ff] = b2[ff];
    #pragma unroll
    for (int k = 0; k < 32; ++k) {
        #pragma unroll
        for (int ff = 0; ff < 32; ++ff)
            y0[ff] = fmaf(t[k], W2[k * FDIM + ff], y0[ff]);
    }

    // t dead — xs0 = x1 (reloaded) + sc*y0b into t
    float sc = silu(c1[0]);
    #pragma unroll
    for (int i = 0; i < 8; ++i) {
        float4 xv = x4[i];
        t[4*i+0] = fmaf(sc, y0[4*i+0], xv.x);
        t[4*i+1] = fmaf(sc, y0[4*i+1], xv.y);
        t[4*i+2] = fmaf(sc, y0[4*i+2], xv.z);
        t[4*i+3] = fmaf(sc, y0[4*i+3], xv.w);
    }

    // y0 dead — reuse as h
    #pragma unroll
    for (int ff = 0; ff < 32; ++ff) y0[ff] = bro1[ff];
    #pragma unroll
    for (int k = 0; k < 32; ++k) {
        #pragma unroll
        for (int ff = 0; ff < 32; ++ff)
            y0[ff] = fmaf(t[k], Wro1[k * FDIM + ff], y0[ff]);
    }

    float p0 = 0.f, p1 = 0.f, p2 = 0.f, p3 = 0.f;
    #pragma unroll
    for (int ff = 0; ff < 32; ff += 4) {
        p0 = fmaf(silu(y0[ff + 0]), Wro2[ff + 0], p0);
        p1 = fmaf(silu(y0[ff + 1]), Wro2[ff + 1], p1);
        p2 = fmaf(silu(y0[ff + 2]), Wro2[ff + 2], p2);
        p3 = fmaf(silu(y0[ff + 3]), Wro2[ff + 3], p3);
    }
    float eatom = (p0 + p1) + (p2 + p3) + bro2[0] + abias[Z[n]];
    atomicAdd(&out[segs[n]], eatom);
}

extern "C" void kernel_launch(void* const* d_in, const int* in_sizes, int n_in,
                              void* d_out, int out_size, void* d_ws, size_t ws_size,
                              hipStream_t stream)
{
    const float* pos     = (const float*)d_in[0];
    const float* embed   = (const float*)d_in[1];
    const float* Wy0     = (const float*)d_in[2];   // (3,32,32) — use [0]
    const float* Wx0     = (const float*)d_in[3];
    const float* W1_0    = (const float*)d_in[4];
    const float* b1_0    = (const float*)d_in[5];
    const float* W2_0    = (const float*)d_in[6];
    const float* b2_0    = (const float*)d_in[7];
    const float* c0      = (const float*)d_in[8];
    const float* Wr_last = (const float*)d_in[9];
    const float* W1_1    = (const float*)d_in[10];
    const float* b1_1    = (const float*)d_in[11];
    const float* W2_1    = (const float*)d_in[12];
    const float* b2_1    = (const float*)d_in[13];
    const float* c1      = (const float*)d_in[14];
    const float* Wro1    = (const float*)d_in[15];
    const float* bro1    = (const float*)d_in[16];
    const float* Wro2    = (const float*)d_in[17];
    const float* bro2    = (const float*)d_in[18];
    const float* abias   = (const float*)d_in[19];
    const int*   Z       = (const int*)d_in[20];
    const int*   dsti    = (const int*)d_in[21];
    const int*   srci    = (const int*)d_in[22];
    const int*   segs    = (const int*)d_in[23];
    // d_in[24] = graph_mask: all-true; where() is identity.

    float* out   = (float*)d_out;
    float* accA  = (float*)d_ws;                  // NNODES*32 floats
    float* accB  = accA + (size_t)NNODES * FDIM;  // NNODES*32 floats
    float* x1buf = accB + (size_t)NNODES * FDIM;  // NNODES*32 floats
    const size_t accBytes = (size_t)NNODES * FDIM * sizeof(float);

    hipMemsetAsync(out, 0, NGRAPHS * sizeof(float), stream);
    hipMemsetAsync(accA, 0, 2 * accBytes, stream);   // accA + accB

    const int edgeBlocks = (NEDGES / 64 + 3) / 4;    // 1563: 1 wave per chunk
    const int nodeBlocks = (NNODES + 255) / 256;     // 196

    // Phase A: accA = sum_e (rbf @ (Wy0[0]+Wx0[0])) * x0[src]
    edge_pass<<<edgeBlocks, 256, 0, stream>>>(pos, srci, dsti, Wy0, Wx0,
                                              embed, Z, accA);
    node_a<<<nodeBlocks, 256, 0, stream>>>(embed, Z, W1_0, b1_0, W2_0, b2_0,
                                           c0, accA, x1buf);
    // Phase B: accB = sum_e (rbf @ Wr_last) * x1[src]
    edge_pass<<<edgeBlocks, 256, 0, stream>>>(pos, srci, dsti, Wr_last, nullptr,
                                              x1buf, nullptr, accB);
    node_b<<<nodeBlocks, 256, 0, stream>>>(W1_1, b1_1, W2_1, b2_1, c1,
                                           Wro1, bro1, Wro2, bro2,
                                           abias, Z, segs, accB, x1buf, out);
}

// Round 6
// 279.249 us; speedup vs baseline: 1.0461x; 1.0461x over previous
//
#include <hip/hip_runtime.h>
#include <math.h>

#define NNODES 50000
#define NEDGES 400000
#define NGRAPHS 512
#define FDIM 32

// C(31, k) exact
__device__ __constant__ float BINOM31[32] = {
    1.f, 31.f, 465.f, 4495.f, 31465.f, 169911.f, 736281.f, 2629575.f,
    7888725.f, 20160075.f, 44352165.f, 84672315.f, 141120525.f, 206253075.f,
    265182525.f, 300540195.f, 300540195.f, 265182525.f, 206253075.f,
    141120525.f, 84672315.f, 44352165.f, 20160075.f, 7888725.f, 2629575.f,
    736281.f, 169911.f, 31465.f, 4495.f, 465.f, 31.f, 1.f
};

__device__ __forceinline__ float fast_rcp(float x) {
    return __builtin_amdgcn_rcpf(x);
}
__device__ __forceinline__ float silu(float x) {
    return x * fast_rcp(1.0f + __expf(-x));
}

// ---------------------------------------------------------------------------
// Edge pass (unchanged from R4): one wave per 64-edge chunk.
// ---------------------------------------------------------------------------
__global__ __launch_bounds__(256) void edge_pass(
    const float* __restrict__ pos,
    const int* __restrict__ src_idx,
    const int* __restrict__ dst_idx,
    const float* __restrict__ Wp1,
    const float* __restrict__ Wp2,      // may be null (pass B)
    const float* __restrict__ xin,
    const int* __restrict__ zmap,       // may be null
    float* __restrict__ acc)
{
    __shared__ float4 quad[4][64];
    int tid  = threadIdx.x;
    int lane = tid & 63;
    int widx = tid >> 6;
    int f    = lane & 31;
    int half = lane >> 5;

    float C[32];
    #pragma unroll
    for (int k = 0; k < 32; ++k) {
        float w = Wp1[k * FDIM + f];
        if (Wp2) w += Wp2[k * FDIM + f];
        C[k] = BINOM31[k] * w;
    }

    int base = (blockIdx.x * 4 + widx) << 6;
    if (base >= NEDGES) return;

    int e = base + lane;                // NEDGES % 64 == 0: in-bounds
    int s = src_idx[e];
    int d = dst_idx[e];
    float dx = pos[3 * s]     - pos[3 * d];
    float dy = pos[3 * s + 1] - pos[3 * d + 1];
    float dz = pos[3 * s + 2] - pos[3 * d + 2];
    float r = sqrtf(dx * dx + dy * dy + dz * dz + 1e-12f);

    float scale = 0.0f;
    if (r < 5.0f) {
        float t = r * 0.2f;
        float q = fmaxf(1.0f - t * t, 1e-7f);
        float cut = __expf(1.0f - fast_rcp(q));
        float v = fast_rcp(r + 1.0f);
        float v2 = v * v, v4 = v2 * v2, v8 = v4 * v4, v16 = v8 * v8;
        scale = v16 * v8 * v4 * v2 * v * cut;
    }
    int row = zmap ? zmap[s] : s;

    quad[widx][lane] = make_float4(scale, r, __int_as_float(row),
                                   __int_as_float(d));

    #pragma unroll
    for (int b = 0; b < 32; b += 8) {
        float4 q[8];
        float xs[8];
        #pragma unroll
        for (int i = 0; i < 8; ++i)
            q[i] = quad[widx][2 * (b + i) + half];
        #pragma unroll
        for (int i = 0; i < 8; ++i)
            xs[i] = xin[__float_as_int(q[i].z) * FDIM + f];
        #pragma unroll
        for (int i = 0; i < 8; ++i) {
            float sj = q[i].x;
            if (sj != 0.0f) {
                float rj = q[i].y;
                float w = C[31];
                #pragma unroll
                for (int k = 30; k >= 0; --k)
                    w = fmaf(w, rj, C[k]);
                atomicAdd(&acc[__float_as_int(q[i].w) * FDIM + f],
                          sj * w * xs[i]);
            }
        }
    }
}

// ---------------------------------------------------------------------------
// Node kernels: quad-per-node (4 lanes, 8 outputs each). Peak liveness ~45
// VGPRs (t[8]+u[8]+stream chunk) -> no spills at any occupancy target.
// Full-vector handoff between matmuls via width-4 shuffles.
// ---------------------------------------------------------------------------
#define LOAD8(dst, ptr)                                                   \
    { float4 _a = *(const float4*)(ptr);                                  \
      float4 _b = *(const float4*)((ptr) + 4);                            \
      dst[0]=_a.x; dst[1]=_a.y; dst[2]=_a.z; dst[3]=_a.w;                 \
      dst[4]=_b.x; dst[5]=_b.y; dst[6]=_b.z; dst[7]=_b.w; }

__global__ __launch_bounds__(256) void node_a(
    const float* __restrict__ embed, const int* __restrict__ Z,
    const float* __restrict__ W1, const float* __restrict__ b1,
    const float* __restrict__ W2, const float* __restrict__ b2,
    const float* __restrict__ c0,
    const float* __restrict__ acc, float* __restrict__ x1buf)
{
    int g = blockIdx.x * blockDim.x + threadIdx.x;
    int n = g >> 2;
    int p8 = (g & 3) * 8;
    if (n >= NNODES) return;

    const float* xrow = embed + (size_t)Z[n] * FDIM;
    const float* arow = acc + (size_t)n * FDIM;

    float t[8];
    LOAD8(t, b1 + p8);
    #pragma unroll
    for (int c = 0; c < 4; ++c) {                 // stream y in chunks of 8
        float xv[8], av[8];
        LOAD8(xv, xrow + c * 8);
        LOAD8(av, arow + c * 8);
        #pragma unroll
        for (int kk = 0; kk < 8; ++kk) {
            float yk = xv[kk] + av[kk];
            const float* wr = W1 + (c * 8 + kk) * FDIM + p8;
            float4 w0 = *(const float4*)(wr);
            float4 w1 = *(const float4*)(wr + 4);
            t[0]=fmaf(yk,w0.x,t[0]); t[1]=fmaf(yk,w0.y,t[1]);
            t[2]=fmaf(yk,w0.z,t[2]); t[3]=fmaf(yk,w0.w,t[3]);
            t[4]=fmaf(yk,w1.x,t[4]); t[5]=fmaf(yk,w1.y,t[5]);
            t[6]=fmaf(yk,w1.z,t[6]); t[7]=fmaf(yk,w1.w,t[7]);
        }
    }
    #pragma unroll
    for (int j = 0; j < 8; ++j) t[j] = silu(t[j]);  // gate@ch0 = silu

    float u[8];
    LOAD8(u, b2 + p8);
    #pragma unroll
    for (int k = 0; k < 32; ++k) {
        float tk = __shfl(t[k & 7], k >> 3, 4);     // quad-local broadcast
        const float* wr = W2 + k * FDIM + p8;
        float4 w0 = *(const float4*)(wr);
        float4 w1 = *(const float4*)(wr + 4);
        u[0]=fmaf(tk,w0.x,u[0]); u[1]=fmaf(tk,w0.y,u[1]);
        u[2]=fmaf(tk,w0.z,u[2]); u[3]=fmaf(tk,w0.w,u[3]);
        u[4]=fmaf(tk,w1.x,u[4]); u[5]=fmaf(tk,w1.y,u[5]);
        u[6]=fmaf(tk,w1.z,u[6]); u[7]=fmaf(tk,w1.w,u[7]);
    }

    float sc = silu(c0[0]);
    float x0s[8];
    LOAD8(x0s, xrow + p8);                          // L1-hot reload of slice
    float4* o4 = (float4*)(x1buf + (size_t)n * FDIM + p8);
    o4[0] = make_float4(fmaf(sc,u[0],x0s[0]), fmaf(sc,u[1],x0s[1]),
                        fmaf(sc,u[2],x0s[2]), fmaf(sc,u[3],x0s[3]));
    o4[1] = make_float4(fmaf(sc,u[4],x0s[4]), fmaf(sc,u[5],x0s[5]),
                        fmaf(sc,u[6],x0s[6]), fmaf(sc,u[7],x0s[7]));
}

__global__ __launch_bounds__(256) void node_b(
    const float* __restrict__ W1, const float* __restrict__ b1,
    const float* __restrict__ W2, const float* __restrict__ b2,
    const float* __restrict__ c1,
    const float* __restrict__ Wro1, const float* __restrict__ bro1,
    const float* __restrict__ Wro2, const float* __restrict__ bro2,
    const float* __restrict__ abias, const int* __restrict__ Z,
    const int* __restrict__ segs,
    const float* __restrict__ acc, const float* __restrict__ x1buf,
    float* __restrict__ out)
{
    int g = blockIdx.x * blockDim.x + threadIdx.x;
    int n = g >> 2;
    int p  = g & 3;
    int p8 = p * 8;
    if (n >= NNODES) return;

    const float* xrow = x1buf + (size_t)n * FDIM;
    const float* arow = acc + (size_t)n * FDIM;

    float t[8];
    LOAD8(t, b1 + p8);
    #pragma unroll
    for (int c = 0; c < 4; ++c) {
        float xv[8], av[8];
        LOAD8(xv, xrow + c * 8);
        LOAD8(av, arow + c * 8);
        #pragma unroll
        for (int kk = 0; kk < 8; ++kk) {
            float yk = xv[kk] + av[kk];
            const float* wr = W1 + (c * 8 + kk) * FDIM + p8;
            float4 w0 = *(const float4*)(wr);
            float4 w1 = *(const float4*)(wr + 4);
            t[0]=fmaf(yk,w0.x,t[0]); t[1]=fmaf(yk,w0.y,t[1]);
            t[2]=fmaf(yk,w0.z,t[2]); t[3]=fmaf(yk,w0.w,t[3]);
            t[4]=fmaf(yk,w1.x,t[4]); t[5]=fmaf(yk,w1.y,t[5]);
            t[6]=fmaf(yk,w1.z,t[6]); t[7]=fmaf(yk,w1.w,t[7]);
        }
    }
    #pragma unroll
    for (int j = 0; j < 8; ++j) t[j] = silu(t[j]);

    float u[8];
    LOAD8(u, b2 + p8);
    #pragma unroll
    for (int k = 0; k < 32; ++k) {
        float tk = __shfl(t[k & 7], k >> 3, 4);
        const float* wr = W2 + k * FDIM + p8;
        float4 w0 = *(const float4*)(wr);
        float4 w1 = *(const float4*)(wr + 4);
        u[0]=fmaf(tk,w0.x,u[0]); u[1]=fmaf(tk,w0.y,u[1]);
        u[2]=fmaf(tk,w0.z,u[2]); u[3]=fmaf(tk,w0.w,u[3]);
        u[4]=fmaf(tk,w1.x,u[4]); u[5]=fmaf(tk,w1.y,u[5]);
        u[6]=fmaf(tk,w1.z,u[6]); u[7]=fmaf(tk,w1.w,u[7]);
    }

    // xs0 slice = x1 slice + silu(c1)*u   (t dead -> reuse)
    float sc = silu(c1[0]);
    {
        float x1s[8];
        LOAD8(x1s, xrow + p8);
        #pragma unroll
        for (int j = 0; j < 8; ++j) t[j] = fmaf(sc, u[j], x1s[j]);
    }

    // h = Wro1^T xs0 + bro1  (u dead -> reuse as h)
    LOAD8(u, bro1 + p8);
    #pragma unroll
    for (int k = 0; k < 32; ++k) {
        float xk = __shfl(t[k & 7], k >> 3, 4);
        const float* wr = Wro1 + k * FDIM + p8;
        float4 w0 = *(const float4*)(wr);
        float4 w1 = *(const float4*)(wr + 4);
        u[0]=fmaf(xk,w0.x,u[0]); u[1]=fmaf(xk,w0.y,u[1]);
        u[2]=fmaf(xk,w0.z,u[2]); u[3]=fmaf(xk,w0.w,u[3]);
        u[4]=fmaf(xk,w1.x,u[4]); u[5]=fmaf(xk,w1.y,u[5]);
        u[6]=fmaf(xk,w1.z,u[6]); u[7]=fmaf(xk,w1.w,u[7]);
    }

    float wv[8];
    LOAD8(wv, Wro2 + p8);
    float part = 0.0f;
    #pragma unroll
    for (int j = 0; j < 8; ++j)
        part = fmaf(silu(u[j]), wv[j], part);
    part += __shfl_xor(part, 1, 4);
    part += __shfl_xor(part, 2, 4);

    if (p == 0) {
        float e = part + bro2[0] + abias[Z[n]];
        atomicAdd(&out[segs[n]], e);
    }
}

extern "C" void kernel_launch(void* const* d_in, const int* in_sizes, int n_in,
                              void* d_out, int out_size, void* d_ws, size_t ws_size,
                              hipStream_t stream)
{
    const float* pos     = (const float*)d_in[0];
    const float* embed   = (const float*)d_in[1];
    const float* Wy0     = (const float*)d_in[2];   // (3,32,32) — use [0]
    const float* Wx0     = (const float*)d_in[3];
    const float* W1_0    = (const float*)d_in[4];
    const float* b1_0    = (const float*)d_in[5];
    const float* W2_0    = (const float*)d_in[6];
    const float* b2_0    = (const float*)d_in[7];
    const float* c0      = (const float*)d_in[8];
    const float* Wr_last = (const float*)d_in[9];
    const float* W1_1    = (const float*)d_in[10];
    const float* b1_1    = (const float*)d_in[11];
    const float* W2_1    = (const float*)d_in[12];
    const float* b2_1    = (const float*)d_in[13];
    const float* c1      = (const float*)d_in[14];
    const float* Wro1    = (const float*)d_in[15];
    const float* bro1    = (const float*)d_in[16];
    const float* Wro2    = (const float*)d_in[17];
    const float* bro2    = (const float*)d_in[18];
    const float* abias   = (const float*)d_in[19];
    const int*   Z       = (const int*)d_in[20];
    const int*   dsti    = (const int*)d_in[21];
    const int*   srci    = (const int*)d_in[22];
    const int*   segs    = (const int*)d_in[23];
    // d_in[24] = graph_mask: all-true; where() is identity.

    float* out   = (float*)d_out;
    float* accA  = (float*)d_ws;                  // NNODES*32 floats
    float* accB  = accA + (size_t)NNODES * FDIM;  // NNODES*32 floats
    float* x1buf = accB + (size_t)NNODES * FDIM;  // NNODES*32 floats
    const size_t accBytes = (size_t)NNODES * FDIM * sizeof(float);

    hipMemsetAsync(out, 0, NGRAPHS * sizeof(float), stream);
    hipMemsetAsync(accA, 0, 2 * accBytes, stream);   // accA + accB

    const int edgeBlocks = (NEDGES / 64 + 3) / 4;      // 1563
    const int nodeBlocks = (NNODES * 4 + 255) / 256;   // 782 (quad-per-node)

    // Phase A: accA = sum_e (rbf @ (Wy0[0]+Wx0[0])) * x0[src]
    edge_pass<<<edgeBlocks, 256, 0, stream>>>(pos, srci, dsti, Wy0, Wx0,
                                              embed, Z, accA);
    node_a<<<nodeBlocks, 256, 0, stream>>>(embed, Z, W1_0, b1_0, W2_0, b2_0,
                                           c0, accA, x1buf);
    // Phase B: accB = sum_e (rbf @ Wr_last) * x1[src]
    edge_pass<<<edgeBlocks, 256, 0, stream>>>(pos, srci, dsti, Wr_last, nullptr,
                                              x1buf, nullptr, accB);
    node_b<<<nodeBlocks, 256, 0, stream>>>(W1_1, b1_1, W2_1, b2_1, c1,
                                           Wro1, bro1, Wro2, bro2,
                                           abias, Z, segs, accB, x1buf, out);
}

// Round 7
// 274.481 us; speedup vs baseline: 1.0642x; 1.0174x over previous
//
#include <hip/hip_runtime.h>
#include <math.h>

#define NNODES 50000
#define NEDGES 400000
#define NGRAPHS 512
#define FDIM 32

// C(31,k) exact — constexpr so uses fold to compile-time immediates.
static constexpr float BINOM31[32] = {
    1.f, 31.f, 465.f, 4495.f, 31465.f, 169911.f, 736281.f, 2629575.f,
    7888725.f, 20160075.f, 44352165.f, 84672315.f, 141120525.f, 206253075.f,
    265182525.f, 300540195.f, 300540195.f, 265182525.f, 206253075.f,
    141120525.f, 84672315.f, 44352165.f, 20160075.f, 7888725.f, 2629575.f,
    736281.f, 169911.f, 31465.f, 4495.f, 465.f, 31.f, 1.f
};

__device__ __forceinline__ float fast_rcp(float x) {
    return __builtin_amdgcn_rcpf(x);
}
__device__ __forceinline__ float silu(float x) {
    return x * fast_rcp(1.0f + __expf(-x));
}

// ---------------------------------------------------------------------------
// Edge pass: one wave per 64-edge chunk. Scalar phase one edge/lane; park
// (scale, r, row, dst) in wave-private LDS. Broadcast phase: 4 edges per
// half-wave per iteration, 4 interleaved named-scalar Horner chains.
// ALL per-thread state is named scalars — nothing the allocator can demote.
// ---------------------------------------------------------------------------
#define DECLC(K) float C##K; { float _w = Wp1[K * FDIM + f];               \
                               if (Wp2) _w += Wp2[K * FDIM + f];           \
                               C##K = BINOM31[K] * _w; }
#define HS(K) wa = fmaf(wa, qa.y, C##K); wb = fmaf(wb, qb.y, C##K);        \
              wc = fmaf(wc, qc.y, C##K); wd = fmaf(wd, qd.y, C##K);

__global__ __launch_bounds__(256, 4) void edge_pass(
    const float* __restrict__ pos,
    const int* __restrict__ src_idx,
    const int* __restrict__ dst_idx,
    const float* __restrict__ Wp1,
    const float* __restrict__ Wp2,      // may be null (pass B)
    const float* __restrict__ xin,
    const int* __restrict__ zmap,       // may be null
    float* __restrict__ acc)
{
    __shared__ float4 quad[4][64];
    int tid  = threadIdx.x;
    int lane = tid & 63;
    int widx = tid >> 6;
    int f    = lane & 31;
    int half = lane >> 5;

    int base = (blockIdx.x * 4 + widx) << 6;
    if (base >= NEDGES) return;

    DECLC(0)  DECLC(1)  DECLC(2)  DECLC(3)  DECLC(4)  DECLC(5)  DECLC(6)
    DECLC(7)  DECLC(8)  DECLC(9)  DECLC(10) DECLC(11) DECLC(12) DECLC(13)
    DECLC(14) DECLC(15) DECLC(16) DECLC(17) DECLC(18) DECLC(19) DECLC(20)
    DECLC(21) DECLC(22) DECLC(23) DECLC(24) DECLC(25) DECLC(26) DECLC(27)
    DECLC(28) DECLC(29) DECLC(30) DECLC(31)

    int e = base + lane;                // NEDGES % 64 == 0: in-bounds
    int s = src_idx[e];
    int d = dst_idx[e];
    float dx = pos[3 * s]     - pos[3 * d];
    float dy = pos[3 * s + 1] - pos[3 * d + 1];
    float dz = pos[3 * s + 2] - pos[3 * d + 2];
    float r = sqrtf(dx * dx + dy * dy + dz * dz + 1e-12f);

    float scale = 0.0f;
    if (r < 5.0f) {
        float t = r * 0.2f;
        float q = fmaxf(1.0f - t * t, 1e-7f);
        float cut = __expf(1.0f - fast_rcp(q));
        float v = fast_rcp(r + 1.0f);
        float v2 = v * v, v4 = v2 * v2, v8 = v4 * v4, v16 = v8 * v8;
        scale = v16 * v8 * v4 * v2 * v * cut;
    }
    int row = zmap ? zmap[s] : s;

    quad[widx][lane] = make_float4(scale, r, __int_as_float(row),
                                   __int_as_float(d));
    // wave-private LDS region, in-wave ordering: no barrier needed.

    #pragma unroll
    for (int b = 0; b < 32; b += 4) {
        float4 qa = quad[widx][2 * (b + 0) + half];
        float4 qb = quad[widx][2 * (b + 1) + half];
        float4 qc = quad[widx][2 * (b + 2) + half];
        float4 qd = quad[widx][2 * (b + 3) + half];
        float xsa = xin[__float_as_int(qa.z) * FDIM + f];
        float xsb = xin[__float_as_int(qb.z) * FDIM + f];
        float xsc = xin[__float_as_int(qc.z) * FDIM + f];
        float xsd = xin[__float_as_int(qd.z) * FDIM + f];
        float wa = C31, wb = C31, wc = C31, wd = C31;
        HS(30) HS(29) HS(28) HS(27) HS(26) HS(25) HS(24) HS(23)
        HS(22) HS(21) HS(20) HS(19) HS(18) HS(17) HS(16) HS(15)
        HS(14) HS(13) HS(12) HS(11) HS(10) HS(9)  HS(8)  HS(7)
        HS(6)  HS(5)  HS(4)  HS(3)  HS(2)  HS(1)  HS(0)
        if (qa.x != 0.0f)
            atomicAdd(&acc[__float_as_int(qa.w) * FDIM + f], qa.x * wa * xsa);
        if (qb.x != 0.0f)
            atomicAdd(&acc[__float_as_int(qb.w) * FDIM + f], qb.x * wb * xsb);
        if (qc.x != 0.0f)
            atomicAdd(&acc[__float_as_int(qc.w) * FDIM + f], qc.x * wc * xsc);
        if (qd.x != 0.0f)
            atomicAdd(&acc[__float_as_int(qd.w) * FDIM + f], qd.x * wd * xsd);
    }
}

// ---------------------------------------------------------------------------
// Node kernels: quad-per-node (4 lanes, 8 outputs each), named scalars only.
// ---------------------------------------------------------------------------
#define FMA8_T(WMAT, K, YK) do {                                           \
    const float* _wr = (WMAT) + (K) * FDIM + p8;                           \
    float4 _wA = *(const float4*)_wr;                                      \
    float4 _wB = *(const float4*)(_wr + 4);                                \
    t0 = fmaf((YK), _wA.x, t0); t1 = fmaf((YK), _wA.y, t1);                \
    t2 = fmaf((YK), _wA.z, t2); t3 = fmaf((YK), _wA.w, t3);                \
    t4 = fmaf((YK), _wB.x, t4); t5 = fmaf((YK), _wB.y, t5);                \
    t6 = fmaf((YK), _wB.z, t6); t7 = fmaf((YK), _wB.w, t7); } while (0)

#define FMA8_U(WMAT, K, YK) do {                                           \
    const float* _wr = (WMAT) + (K) * FDIM + p8;                           \
    float4 _wA = *(const float4*)_wr;                                      \
    float4 _wB = *(const float4*)(_wr + 4);                                \
    u0 = fmaf((YK), _wA.x, u0); u1 = fmaf((YK), _wA.y, u1);                \
    u2 = fmaf((YK), _wA.z, u2); u3 = fmaf((YK), _wA.w, u3);                \
    u4 = fmaf((YK), _wB.x, u4); u5 = fmaf((YK), _wB.y, u5);                \
    u6 = fmaf((YK), _wB.z, u6); u7 = fmaf((YK), _wB.w, u7); } while (0)

// Matmul1: stream y in chunks of 8 (chunk c), accumulate into t0..t7.
#define MM1_CHUNK(WMAT, XROW, AROW, c) do {                                \
    float4 _xA = *(const float4*)((XROW) + (c) * 8);                       \
    float4 _xB = *(const float4*)((XROW) + (c) * 8 + 4);                   \
    float4 _aA = *(const float4*)((AROW) + (c) * 8);                       \
    float4 _aB = *(const float4*)((AROW) + (c) * 8 + 4);                   \
    FMA8_T(WMAT, (c) * 8 + 0, _xA.x + _aA.x);                              \
    FMA8_T(WMAT, (c) * 8 + 1, _xA.y + _aA.y);                              \
    FMA8_T(WMAT, (c) * 8 + 2, _xA.z + _aA.z);                              \
    FMA8_T(WMAT, (c) * 8 + 3, _xA.w + _aA.w);                              \
    FMA8_T(WMAT, (c) * 8 + 4, _xB.x + _aB.x);                              \
    FMA8_T(WMAT, (c) * 8 + 5, _xB.y + _aB.y);                              \
    FMA8_T(WMAT, (c) * 8 + 6, _xB.z + _aB.z);                              \
    FMA8_T(WMAT, (c) * 8 + 7, _xB.w + _aB.w); } while (0)

// Matmul from quad-distributed vector t (lane Q holds elems 8Q..8Q+7) into u.
#define QROW_U(WMAT, Q)                                                    \
    FMA8_U(WMAT, 8 * (Q) + 0, __shfl(t0, (Q), 4));                         \
    FMA8_U(WMAT, 8 * (Q) + 1, __shfl(t1, (Q), 4));                         \
    FMA8_U(WMAT, 8 * (Q) + 2, __shfl(t2, (Q), 4));                         \
    FMA8_U(WMAT, 8 * (Q) + 3, __shfl(t3, (Q), 4));                         \
    FMA8_U(WMAT, 8 * (Q) + 4, __shfl(t4, (Q), 4));                         \
    FMA8_U(WMAT, 8 * (Q) + 5, __shfl(t5, (Q), 4));                         \
    FMA8_U(WMAT, 8 * (Q) + 6, __shfl(t6, (Q), 4));                         \
    FMA8_U(WMAT, 8 * (Q) + 7, __shfl(t7, (Q), 4));

__global__ __launch_bounds__(256, 4) void node_a(
    const float* __restrict__ embed, const int* __restrict__ Z,
    const float* __restrict__ W1, const float* __restrict__ b1,
    const float* __restrict__ W2, const float* __restrict__ b2,
    const float* __restrict__ c0,
    const float* __restrict__ acc, float* __restrict__ x1buf)
{
    int g = blockIdx.x * blockDim.x + threadIdx.x;
    int n = g >> 2;
    int p8 = (g & 3) * 8;
    if (n >= NNODES) return;

    const float* xrow = embed + (size_t)Z[n] * FDIM;
    const float* arow = acc + (size_t)n * FDIM;

    float4 bA = *(const float4*)(b1 + p8);
    float4 bB = *(const float4*)(b1 + p8 + 4);
    float t0 = bA.x, t1 = bA.y, t2 = bA.z, t3 = bA.w;
    float t4 = bB.x, t5 = bB.y, t6 = bB.z, t7 = bB.w;
    MM1_CHUNK(W1, xrow, arow, 0);
    MM1_CHUNK(W1, xrow, arow, 1);
    MM1_CHUNK(W1, xrow, arow, 2);
    MM1_CHUNK(W1, xrow, arow, 3);
    t0 = silu(t0); t1 = silu(t1); t2 = silu(t2); t3 = silu(t3);
    t4 = silu(t4); t5 = silu(t5); t6 = silu(t6); t7 = silu(t7);

    float4 cA = *(const float4*)(b2 + p8);
    float4 cB = *(const float4*)(b2 + p8 + 4);
    float u0 = cA.x, u1 = cA.y, u2 = cA.z, u3 = cA.w;
    float u4 = cB.x, u5 = cB.y, u6 = cB.z, u7 = cB.w;
    QROW_U(W2, 0) QROW_U(W2, 1) QROW_U(W2, 2) QROW_U(W2, 3)

    float sc = silu(c0[0]);
    float4 xA = *(const float4*)(xrow + p8);
    float4 xB = *(const float4*)(xrow + p8 + 4);
    float4* o4 = (float4*)(x1buf + (size_t)n * FDIM + p8);
    o4[0] = make_float4(fmaf(sc, u0, xA.x), fmaf(sc, u1, xA.y),
                        fmaf(sc, u2, xA.z), fmaf(sc, u3, xA.w));
    o4[1] = make_float4(fmaf(sc, u4, xB.x), fmaf(sc, u5, xB.y),
                        fmaf(sc, u6, xB.z), fmaf(sc, u7, xB.w));
}

__global__ __launch_bounds__(256, 4) void node_b(
    const float* __restrict__ W1, const float* __restrict__ b1,
    const float* __restrict__ W2, const float* __restrict__ b2,
    const float* __restrict__ c1,
    const float* __restrict__ Wro1, const float* __restrict__ bro1,
    const float* __restrict__ Wro2, const float* __restrict__ bro2,
    const float* __restrict__ abias, const int* __restrict__ Z,
    const int* __restrict__ segs,
    const float* __restrict__ acc, const float* __restrict__ x1buf,
    float* __restrict__ out)
{
    int g = blockIdx.x * blockDim.x + threadIdx.x;
    int n = g >> 2;
    int p  = g & 3;
    int p8 = p * 8;
    if (n >= NNODES) return;

    const float* xrow = x1buf + (size_t)n * FDIM;
    const float* arow = acc + (size_t)n * FDIM;

    float4 bA = *(const float4*)(b1 + p8);
    float4 bB = *(const float4*)(b1 + p8 + 4);
    float t0 = bA.x, t1 = bA.y, t2 = bA.z, t3 = bA.w;
    float t4 = bB.x, t5 = bB.y, t6 = bB.z, t7 = bB.w;
    MM1_CHUNK(W1, xrow, arow, 0);
    MM1_CHUNK(W1, xrow, arow, 1);
    MM1_CHUNK(W1, xrow, arow, 2);
    MM1_CHUNK(W1, xrow, arow, 3);
    t0 = silu(t0); t1 = silu(t1); t2 = silu(t2); t3 = silu(t3);
    t4 = silu(t4); t5 = silu(t5); t6 = silu(t6); t7 = silu(t7);

    float4 cA = *(const float4*)(b2 + p8);
    float4 cB = *(const float4*)(b2 + p8 + 4);
    float u0 = cA.x, u1 = cA.y, u2 = cA.z, u3 = cA.w;
    float u4 = cB.x, u5 = cB.y, u6 = cB.z, u7 = cB.w;
    QROW_U(W2, 0) QROW_U(W2, 1) QROW_U(W2, 2) QROW_U(W2, 3)

    // xs0 slice -> t (t dead after matmul2 shuffles)
    float sc = silu(c1[0]);
    {
        float4 xA = *(const float4*)(xrow + p8);
        float4 xB = *(const float4*)(xrow + p8 + 4);
        t0 = fmaf(sc, u0, xA.x); t1 = fmaf(sc, u1, xA.y);
        t2 = fmaf(sc, u2, xA.z); t3 = fmaf(sc, u3, xA.w);
        t4 = fmaf(sc, u4, xB.x); t5 = fmaf(sc, u5, xB.y);
        t6 = fmaf(sc, u6, xB.z); t7 = fmaf(sc, u7, xB.w);
    }

    // h = Wro1^T xs0 + bro1 -> u
    {
        float4 hA = *(const float4*)(bro1 + p8);
        float4 hB = *(const float4*)(bro1 + p8 + 4);
        u0 = hA.x; u1 = hA.y; u2 = hA.z; u3 = hA.w;
        u4 = hB.x; u5 = hB.y; u6 = hB.z; u7 = hB.w;
    }
    QROW_U(Wro1, 0) QROW_U(Wro1, 1) QROW_U(Wro1, 2) QROW_U(Wro1, 3)

    float4 wA = *(const float4*)(Wro2 + p8);
    float4 wB = *(const float4*)(Wro2 + p8 + 4);
    float part = silu(u0) * wA.x;
    part = fmaf(silu(u1), wA.y, part);
    part = fmaf(silu(u2), wA.z, part);
    part = fmaf(silu(u3), wA.w, part);
    part = fmaf(silu(u4), wB.x, part);
    part = fmaf(silu(u5), wB.y, part);
    part = fmaf(silu(u6), wB.z, part);
    part = fmaf(silu(u7), wB.w, part);
    part += __shfl_xor(part, 1, 4);
    part += __shfl_xor(part, 2, 4);

    if (p == 0) {
        float e = part + bro2[0] + abias[Z[n]];
        atomicAdd(&out[segs[n]], e);
    }
}

extern "C" void kernel_launch(void* const* d_in, const int* in_sizes, int n_in,
                              void* d_out, int out_size, void* d_ws, size_t ws_size,
                              hipStream_t stream)
{
    const float* pos     = (const float*)d_in[0];
    const float* embed   = (const float*)d_in[1];
    const float* Wy0     = (const float*)d_in[2];   // (3,32,32) — use [0]
    const float* Wx0     = (const float*)d_in[3];
    const float* W1_0    = (const float*)d_in[4];
    const float* b1_0    = (const float*)d_in[5];
    const float* W2_0    = (const float*)d_in[6];
    const float* b2_0    = (const float*)d_in[7];
    const float* c0      = (const float*)d_in[8];
    const float* Wr_last = (const float*)d_in[9];
    const float* W1_1    = (const float*)d_in[10];
    const float* b1_1    = (const float*)d_in[11];
    const float* W2_1    = (const float*)d_in[12];
    const float* b2_1    = (const float*)d_in[13];
    const float* c1      = (const float*)d_in[14];
    const float* Wro1    = (const float*)d_in[15];
    const float* bro1    = (const float*)d_in[16];
    const float* Wro2    = (const float*)d_in[17];
    const float* bro2    = (const float*)d_in[18];
    const float* abias   = (const float*)d_in[19];
    const int*   Z       = (const int*)d_in[20];
    const int*   dsti    = (const int*)d_in[21];
    const int*   srci    = (const int*)d_in[22];
    const int*   segs    = (const int*)d_in[23];
    // d_in[24] = graph_mask: all-true; where() is identity.

    float* out   = (float*)d_out;
    float* accA  = (float*)d_ws;                  // NNODES*32 floats
    float* accB  = accA + (size_t)NNODES * FDIM;  // NNODES*32 floats
    float* x1buf = accB + (size_t)NNODES * FDIM;  // NNODES*32 floats
    const size_t accBytes = (size_t)NNODES * FDIM * sizeof(float);

    hipMemsetAsync(out, 0, NGRAPHS * sizeof(float), stream);
    hipMemsetAsync(accA, 0, 2 * accBytes, stream);   // accA + accB

    const int edgeBlocks = (NEDGES / 64 + 3) / 4;      // 1563
    const int nodeBlocks = (NNODES * 4 + 255) / 256;   // 782 (quad-per-node)

    // Phase A: accA = sum_e (rbf @ (Wy0[0]+Wx0[0])) * x0[src]
    edge_pass<<<edgeBlocks, 256, 0, stream>>>(pos, srci, dsti, Wy0, Wx0,
                                              embed, Z, accA);
    node_a<<<nodeBlocks, 256, 0, stream>>>(embed, Z, W1_0, b1_0, W2_0, b2_0,
                                           c0, accA, x1buf);
    // Phase B: accB = sum_e (rbf @ Wr_last) * x1[src]
    edge_pass<<<edgeBlocks, 256, 0, stream>>>(pos, srci, dsti, Wr_last, nullptr,
                                              x1buf, nullptr, accB);
    node_b<<<nodeBlocks, 256, 0, stream>>>(W1_1, b1_1, W2_1, b2_1, c1,
                                           Wro1, bro1, Wro2, bro2,
                                           abias, Z, segs, accB, x1buf, out);
}

// Round 8
// 267.473 us; speedup vs baseline: 1.0921x; 1.0262x over previous
//
#include <hip/hip_runtime.h>
#include <math.h>

#define NNODES 50000
#define NEDGES 400000
#define NGRAPHS 512
#define FDIM 32

// C(31,k) exact — constexpr so uses fold to compile-time immediates.
static constexpr float BINOM31[32] = {
    1.f, 31.f, 465.f, 4495.f, 31465.f, 169911.f, 736281.f, 2629575.f,
    7888725.f, 20160075.f, 44352165.f, 84672315.f, 141120525.f, 206253075.f,
    265182525.f, 300540195.f, 300540195.f, 265182525.f, 206253075.f,
    141120525.f, 84672315.f, 44352165.f, 20160075.f, 7888725.f, 2629575.f,
    736281.f, 169911.f, 31465.f, 4495.f, 465.f, 31.f, 1.f
};

__device__ __forceinline__ float fast_rcp(float x) {
    return __builtin_amdgcn_rcpf(x);
}
__device__ __forceinline__ float silu(float x) {
    return x * fast_rcp(1.0f + __expf(-x));
}

// ---------------------------------------------------------------------------
// Edge pass (unchanged from R7): one wave per 64-edge chunk, named-scalar
// Horner coefficients, 4-way-interleaved broadcast phase.
// ---------------------------------------------------------------------------
#define DECLC(K) float C##K; { float _w = Wp1[K * FDIM + f];               \
                               if (Wp2) _w += Wp2[K * FDIM + f];           \
                               C##K = BINOM31[K] * _w; }
#define HS(K) wa = fmaf(wa, qa.y, C##K); wb = fmaf(wb, qb.y, C##K);        \
              wc = fmaf(wc, qc.y, C##K); wd = fmaf(wd, qd.y, C##K);

__global__ __launch_bounds__(256, 4) void edge_pass(
    const float* __restrict__ pos,
    const int* __restrict__ src_idx,
    const int* __restrict__ dst_idx,
    const float* __restrict__ Wp1,
    const float* __restrict__ Wp2,      // may be null (pass B)
    const float* __restrict__ xin,
    const int* __restrict__ zmap,       // may be null
    float* __restrict__ acc)
{
    __shared__ float4 quad[4][64];
    int tid  = threadIdx.x;
    int lane = tid & 63;
    int widx = tid >> 6;
    int f    = lane & 31;
    int half = lane >> 5;

    int base = (blockIdx.x * 4 + widx) << 6;
    if (base >= NEDGES) return;

    DECLC(0)  DECLC(1)  DECLC(2)  DECLC(3)  DECLC(4)  DECLC(5)  DECLC(6)
    DECLC(7)  DECLC(8)  DECLC(9)  DECLC(10) DECLC(11) DECLC(12) DECLC(13)
    DECLC(14) DECLC(15) DECLC(16) DECLC(17) DECLC(18) DECLC(19) DECLC(20)
    DECLC(21) DECLC(22) DECLC(23) DECLC(24) DECLC(25) DECLC(26) DECLC(27)
    DECLC(28) DECLC(29) DECLC(30) DECLC(31)

    int e = base + lane;                // NEDGES % 64 == 0: in-bounds
    int s = src_idx[e];
    int d = dst_idx[e];
    float dx = pos[3 * s]     - pos[3 * d];
    float dy = pos[3 * s + 1] - pos[3 * d + 1];
    float dz = pos[3 * s + 2] - pos[3 * d + 2];
    float r = sqrtf(dx * dx + dy * dy + dz * dz + 1e-12f);

    float scale = 0.0f;
    if (r < 5.0f) {
        float t = r * 0.2f;
        float q = fmaxf(1.0f - t * t, 1e-7f);
        float cut = __expf(1.0f - fast_rcp(q));
        float v = fast_rcp(r + 1.0f);
        float v2 = v * v, v4 = v2 * v2, v8 = v4 * v4, v16 = v8 * v8;
        scale = v16 * v8 * v4 * v2 * v * cut;
    }
    int row = zmap ? zmap[s] : s;

    quad[widx][lane] = make_float4(scale, r, __int_as_float(row),
                                   __int_as_float(d));
    // wave-private LDS region, in-wave ordering: no barrier needed.

    #pragma unroll
    for (int b = 0; b < 32; b += 4) {
        float4 qa = quad[widx][2 * (b + 0) + half];
        float4 qb = quad[widx][2 * (b + 1) + half];
        float4 qc = quad[widx][2 * (b + 2) + half];
        float4 qd = quad[widx][2 * (b + 3) + half];
        float xsa = xin[__float_as_int(qa.z) * FDIM + f];
        float xsb = xin[__float_as_int(qb.z) * FDIM + f];
        float xsc = xin[__float_as_int(qc.z) * FDIM + f];
        float xsd = xin[__float_as_int(qd.z) * FDIM + f];
        float wa = C31, wb = C31, wc = C31, wd = C31;
        HS(30) HS(29) HS(28) HS(27) HS(26) HS(25) HS(24) HS(23)
        HS(22) HS(21) HS(20) HS(19) HS(18) HS(17) HS(16) HS(15)
        HS(14) HS(13) HS(12) HS(11) HS(10) HS(9)  HS(8)  HS(7)
        HS(6)  HS(5)  HS(4)  HS(3)  HS(2)  HS(1)  HS(0)
        if (qa.x != 0.0f)
            atomicAdd(&acc[__float_as_int(qa.w) * FDIM + f], qa.x * wa * xsa);
        if (qb.x != 0.0f)
            atomicAdd(&acc[__float_as_int(qb.w) * FDIM + f], qb.x * wb * xsb);
        if (qc.x != 0.0f)
            atomicAdd(&acc[__float_as_int(qc.w) * FDIM + f], qc.x * wc * xsc);
        if (qd.x != 0.0f)
            atomicAdd(&acc[__float_as_int(qd.w) * FDIM + f], qd.x * wd * xsd);
    }
}

// ---------------------------------------------------------------------------
// Node kernels: persistent waves, one node per 32-lane half. Lane f owns
// output feature f; W COLUMNS live in named registers loaded ONCE per wave.
// Layer handoff via wave-private LDS row: 1 ds_write_b32 publish + 8
// broadcast ds_read_b128 per matvec. No barriers, no bpermute matvecs.
// ---------------------------------------------------------------------------
#define COLS(P, MAT)                                                       \
    float P##0  = (MAT)[ 0*FDIM+f], P##1  = (MAT)[ 1*FDIM+f],              \
          P##2  = (MAT)[ 2*FDIM+f], P##3  = (MAT)[ 3*FDIM+f],              \
          P##4  = (MAT)[ 4*FDIM+f], P##5  = (MAT)[ 5*FDIM+f],              \
          P##6  = (MAT)[ 6*FDIM+f], P##7  = (MAT)[ 7*FDIM+f],              \
          P##8  = (MAT)[ 8*FDIM+f], P##9  = (MAT)[ 9*FDIM+f],              \
          P##10 = (MAT)[10*FDIM+f], P##11 = (MAT)[11*FDIM+f],              \
          P##12 = (MAT)[12*FDIM+f], P##13 = (MAT)[13*FDIM+f],              \
          P##14 = (MAT)[14*FDIM+f], P##15 = (MAT)[15*FDIM+f],              \
          P##16 = (MAT)[16*FDIM+f], P##17 = (MAT)[17*FDIM+f],              \
          P##18 = (MAT)[18*FDIM+f], P##19 = (MAT)[19*FDIM+f],              \
          P##20 = (MAT)[20*FDIM+f], P##21 = (MAT)[21*FDIM+f],              \
          P##22 = (MAT)[22*FDIM+f], P##23 = (MAT)[23*FDIM+f],              \
          P##24 = (MAT)[24*FDIM+f], P##25 = (MAT)[25*FDIM+f],              \
          P##26 = (MAT)[26*FDIM+f], P##27 = (MAT)[27*FDIM+f],              \
          P##28 = (MAT)[28*FDIM+f], P##29 = (MAT)[29*FDIM+f],              \
          P##30 = (MAT)[30*FDIM+f], P##31 = (MAT)[31*FDIM+f];

// RES = bias + sum_k y[k]*P_k, y read from LDS as 8 broadcast float4,
// 4 independent FMA chains for ILP.
#define MATVEC32(RES, P, YP, BIAS) do {                                    \
    float4 _q0=(YP)[0], _q1=(YP)[1], _q2=(YP)[2], _q3=(YP)[3];             \
    float4 _q4=(YP)[4], _q5=(YP)[5], _q6=(YP)[6], _q7=(YP)[7];             \
    float _a0=(BIAS), _a1=0.f, _a2=0.f, _a3=0.f;                           \
    _a0=fmaf(_q0.x,P##0,_a0);  _a0=fmaf(_q0.y,P##1,_a0);                   \
    _a0=fmaf(_q0.z,P##2,_a0);  _a0=fmaf(_q0.w,P##3,_a0);                   \
    _a1=fmaf(_q1.x,P##4,_a1);  _a1=fmaf(_q1.y,P##5,_a1);                   \
    _a1=fmaf(_q1.z,P##6,_a1);  _a1=fmaf(_q1.w,P##7,_a1);                   \
    _a2=fmaf(_q2.x,P##8,_a2);  _a2=fmaf(_q2.y,P##9,_a2);                   \
    _a2=fmaf(_q2.z,P##10,_a2); _a2=fmaf(_q2.w,P##11,_a2);                  \
    _a3=fmaf(_q3.x,P##12,_a3); _a3=fmaf(_q3.y,P##13,_a3);                  \
    _a3=fmaf(_q3.z,P##14,_a3); _a3=fmaf(_q3.w,P##15,_a3);                  \
    _a0=fmaf(_q4.x,P##16,_a0); _a0=fmaf(_q4.y,P##17,_a0);                  \
    _a0=fmaf(_q4.z,P##18,_a0); _a0=fmaf(_q4.w,P##19,_a0);                  \
    _a1=fmaf(_q5.x,P##20,_a1); _a1=fmaf(_q5.y,P##21,_a1);                  \
    _a1=fmaf(_q5.z,P##22,_a1); _a1=fmaf(_q5.w,P##23,_a1);                  \
    _a2=fmaf(_q6.x,P##24,_a2); _a2=fmaf(_q6.y,P##25,_a2);                  \
    _a2=fmaf(_q6.z,P##26,_a2); _a2=fmaf(_q6.w,P##27,_a2);                  \
    _a3=fmaf(_q7.x,P##28,_a3); _a3=fmaf(_q7.y,P##29,_a3);                  \
    _a3=fmaf(_q7.z,P##30,_a3); _a3=fmaf(_q7.w,P##31,_a3);                  \
    RES = (_a0+_a1)+(_a2+_a3); } while (0)

__global__ __launch_bounds__(256, 3) void node_a(
    const float* __restrict__ embed, const int* __restrict__ Z,
    const float* __restrict__ W1, const float* __restrict__ b1,
    const float* __restrict__ W2, const float* __restrict__ b2,
    const float* __restrict__ c0,
    const float* __restrict__ acc, float* __restrict__ x1buf)
{
    __shared__ __align__(16) float ylds[4][64];
    int tid  = threadIdx.x;
    int widx = tid >> 6;
    int lane = tid & 63;
    int f    = lane & 31;
    int half = lane >> 5;

    COLS(A, W1)
    COLS(B, W2)
    float b1f = b1[f], b2f = b2[f];
    float sc = silu(c0[0]);

    float* yrow = &ylds[widx][half * 32];
    const float4* yp = (const float4*)yrow;

    int wid    = blockIdx.x * 4 + widx;
    int nwaves = gridDim.x * 4;

    for (int pair = wid * 2; pair < NNODES; pair += nwaves * 2) {
        int n = pair + half;
        bool act = (n < NNODES);
        float x0 = 0.f, yv = 0.f;
        if (act) {
            x0 = embed[Z[n] * FDIM + f];
            yv = x0 + acc[(size_t)n * FDIM + f];
        }
        yrow[f] = yv;                    // publish y (in-wave DS ordering)
        float t;
        MATVEC32(t, A, yp, b1f);
        t = silu(t);                     // gate@ch0 = silu
        yrow[f] = t;                     // publish t
        float u;
        MATVEC32(u, B, yp, b2f);
        if (act)
            x1buf[(size_t)n * FDIM + f] = fmaf(sc, u, x0);
    }
}

__global__ __launch_bounds__(256, 3) void node_b(
    const float* __restrict__ W1, const float* __restrict__ b1,
    const float* __restrict__ W2, const float* __restrict__ b2,
    const float* __restrict__ c1,
    const float* __restrict__ Wro1, const float* __restrict__ bro1,
    const float* __restrict__ Wro2, const float* __restrict__ bro2,
    const float* __restrict__ abias, const int* __restrict__ Z,
    const int* __restrict__ segs,
    const float* __restrict__ acc, const float* __restrict__ x1buf,
    float* __restrict__ out)
{
    __shared__ __align__(16) float ylds[4][64];
    int tid  = threadIdx.x;
    int widx = tid >> 6;
    int lane = tid & 63;
    int f    = lane & 31;
    int half = lane >> 5;

    COLS(A, W1)
    COLS(B, W2)
    COLS(R, Wro1)
    float b1f = b1[f], b2f = b2[f], brf = bro1[f], w2f = Wro2[f];
    float sc  = silu(c1[0]);
    float br2 = bro2[0];

    float* yrow = &ylds[widx][half * 32];
    const float4* yp = (const float4*)yrow;

    int wid    = blockIdx.x * 4 + widx;
    int nwaves = gridDim.x * 4;

    for (int pair = wid * 2; pair < NNODES; pair += nwaves * 2) {
        int n = pair + half;
        bool act = (n < NNODES);
        float x1 = 0.f, yv = 0.f;
        if (act) {
            x1 = x1buf[(size_t)n * FDIM + f];
            yv = x1 + acc[(size_t)n * FDIM + f];
        }
        yrow[f] = yv;                    // publish y0
        float t;
        MATVEC32(t, A, yp, b1f);
        t = silu(t);
        yrow[f] = t;                     // publish t
        float u;
        MATVEC32(u, B, yp, b2f);
        float xs0 = fmaf(sc, u, x1);
        yrow[f] = xs0;                   // publish xs0
        float h;
        MATVEC32(h, R, yp, brf);
        float p = silu(h) * w2f;
        p += __shfl_xor(p, 16, 32);
        p += __shfl_xor(p, 8, 32);
        p += __shfl_xor(p, 4, 32);
        p += __shfl_xor(p, 2, 32);
        p += __shfl_xor(p, 1, 32);
        if (act && f == 0) {
            float e = p + br2 + abias[Z[n]];
            atomicAdd(&out[segs[n]], e);
        }
    }
}

extern "C" void kernel_launch(void* const* d_in, const int* in_sizes, int n_in,
                              void* d_out, int out_size, void* d_ws, size_t ws_size,
                              hipStream_t stream)
{
    const float* pos     = (const float*)d_in[0];
    const float* embed   = (const float*)d_in[1];
    const float* Wy0     = (const float*)d_in[2];   // (3,32,32) — use [0]
    const float* Wx0     = (const float*)d_in[3];
    const float* W1_0    = (const float*)d_in[4];
    const float* b1_0    = (const float*)d_in[5];
    const float* W2_0    = (const float*)d_in[6];
    const float* b2_0    = (const float*)d_in[7];
    const float* c0      = (const float*)d_in[8];
    const float* Wr_last = (const float*)d_in[9];
    const float* W1_1    = (const float*)d_in[10];
    const float* b1_1    = (const float*)d_in[11];
    const float* W2_1    = (const float*)d_in[12];
    const float* b2_1    = (const float*)d_in[13];
    const float* c1      = (const float*)d_in[14];
    const float* Wro1    = (const float*)d_in[15];
    const float* bro1    = (const float*)d_in[16];
    const float* Wro2    = (const float*)d_in[17];
    const float* bro2    = (const float*)d_in[18];
    const float* abias   = (const float*)d_in[19];
    const int*   Z       = (const int*)d_in[20];
    const int*   dsti    = (const int*)d_in[21];
    const int*   srci    = (const int*)d_in[22];
    const int*   segs    = (const int*)d_in[23];
    // d_in[24] = graph_mask: all-true; where() is identity.

    float* out   = (float*)d_out;
    float* accA  = (float*)d_ws;                  // NNODES*32 floats
    float* accB  = accA + (size_t)NNODES * FDIM;  // NNODES*32 floats
    float* x1buf = accB + (size_t)NNODES * FDIM;  // NNODES*32 floats
    const size_t accBytes = (size_t)NNODES * FDIM * sizeof(float);

    hipMemsetAsync(out, 0, NGRAPHS * sizeof(float), stream);
    hipMemsetAsync(accA, 0, 2 * accBytes, stream);   // accA + accB

    const int edgeBlocks = (NEDGES / 64 + 3) / 4;    // 1563
    const int nodeBlocks = 1024;                     // 4096 persistent waves

    // Phase A: accA = sum_e (rbf @ (Wy0[0]+Wx0[0])) * x0[src]
    edge_pass<<<edgeBlocks, 256, 0, stream>>>(pos, srci, dsti, Wy0, Wx0,
                                              embed, Z, accA);
    node_a<<<nodeBlocks, 256, 0, stream>>>(embed, Z, W1_0, b1_0, W2_0, b2_0,
                                           c0, accA, x1buf);
    // Phase B: accB = sum_e (rbf @ Wr_last) * x1[src]
    edge_pass<<<edgeBlocks, 256, 0, stream>>>(pos, srci, dsti, Wr_last, nullptr,
                                              x1buf, nullptr, accB);
    node_b<<<nodeBlocks, 256, 0, stream>>>(W1_1, b1_1, W2_1, b2_1, c1,
                                           Wro1, bro1, Wro2, bro2,
                                           abias, Z, segs, accB, x1buf, out);
}